// Round 6
// baseline (242.118 us; speedup 1.0000x reference)
//
#include <hip/hip_runtime.h>
#include <stdint.h>

typedef __bf16 bf16;
typedef __bf16 bf16x8 __attribute__((ext_vector_type(8)));
typedef float f32x4 __attribute__((ext_vector_type(4)));

#define AS1 __attribute__((address_space(1)))
#define AS3 __attribute__((address_space(3)))

__device__ __forceinline__ void gload_lds16(const void* g, void* l) {
    __builtin_amdgcn_global_load_lds((const AS1 uint32_t*)g, (AS3 uint32_t*)l, 16, 0, 0);
}

// ---------------------------------------------------------------------------
// NT GEMM: C[m,n] = sum_k A[m,k]*B[n,k] + bias[n]  (unchanged from R5)
// BM=128, BN=64, BK=64 -> grid 64x16 = 1024 blocks = 4 blocks/CU.
// ---------------------------------------------------------------------------
#define BM 128
#define BN 64
#define BK 64

template <typename OT>
__global__ __launch_bounds__(256, 4) void gemm_nt(
    const bf16* __restrict__ A, const bf16* __restrict__ B,
    const float* __restrict__ bias, OT* __restrict__ C,
    int M, int N, int K)
{
    __shared__ bf16 smA[BM * BK];   // 16 KB
    __shared__ bf16 smB[BN * BK];   //  8 KB

    const int tid  = threadIdx.x;
    const int wave = tid >> 6;
    const int lane = tid & 63;
    const int wm = (wave >> 1) * 64;
    const int wn = (wave & 1) * 32;
    const int rowA0 = blockIdx.x * BM;
    const int rowB0 = blockIdx.y * BN;

    f32x4 acc[4][2] = {};

    const int g  = lane >> 4;
    const int rm = lane & 15;

    for (int k0 = 0; k0 < K; k0 += BK) {
        #pragma unroll
        for (int i = 0; i < 4; ++i) {
            int slot = i * 256 + tid;
            int row  = slot >> 3;
            int kg   = slot & 7;
            int kd   = kg ^ ((row >> 1) & 7);
            gload_lds16(A + (size_t)(rowA0 + row) * K + k0 + kd * 8, &smA[slot * 8]);
        }
        #pragma unroll
        for (int i = 0; i < 2; ++i) {
            int slot = i * 256 + tid;
            int row  = slot >> 3;
            int kg   = slot & 7;
            int kd   = kg ^ ((row >> 1) & 7);
            gload_lds16(B + (size_t)(rowB0 + row) * K + k0 + kd * 8, &smB[slot * 8]);
        }
        __syncthreads();

        #pragma unroll
        for (int s = 0; s < 2; ++s) {
            bf16x8 af[4], bfr[2];
            #pragma unroll
            for (int mi = 0; mi < 4; ++mi) {
                int row  = wm + mi * 16 + rm;
                int slot = row * 8 + ((s * 4 + g) ^ ((row >> 1) & 7));
                af[mi] = *(const bf16x8*)&smA[slot * 8];
            }
            #pragma unroll
            for (int ni = 0; ni < 2; ++ni) {
                int row  = wn + ni * 16 + rm;
                int slot = row * 8 + ((s * 4 + g) ^ ((row >> 1) & 7));
                bfr[ni] = *(const bf16x8*)&smB[slot * 8];
            }
            #pragma unroll
            for (int mi = 0; mi < 4; ++mi)
                #pragma unroll
                for (int ni = 0; ni < 2; ++ni)
                    acc[mi][ni] = __builtin_amdgcn_mfma_f32_16x16x32_bf16(
                        af[mi], bfr[ni], acc[mi][ni], 0, 0, 0);
        }
        __syncthreads();
    }

    const int quad = lane >> 4;
    #pragma unroll
    for (int ni = 0; ni < 2; ++ni) {
        int col = rowB0 + wn + ni * 16 + rm;
        float bcol = bias[col];
        #pragma unroll
        for (int mi = 0; mi < 4; ++mi) {
            #pragma unroll
            for (int r = 0; r < 4; ++r) {
                int rowc = rowA0 + wm + mi * 16 + quad * 4 + r;
                C[(size_t)rowc * N + col] = (OT)(acc[mi][ni][r] + bcol);
            }
        }
    }
}

// ---------------------------------------------------------------------------
// fused fp32 -> bf16 cast of x, W_in, W_out (one launch)
// ---------------------------------------------------------------------------
__global__ void cast_all_kernel(const float* __restrict__ x, bf16* __restrict__ xb,
                                const float* __restrict__ wi, bf16* __restrict__ wib,
                                const float* __restrict__ wo, bf16* __restrict__ wob)
{
    const int NX8 = (2 * 4096 * 1024) / 8;
    const int NW8 = (1024 * 1024) / 8;
    int i = blockIdx.x * 256 + threadIdx.x;
    const float* in; bf16* out; int idx;
    if (i < NX8)            { in = x;  out = xb;  idx = i; }
    else if (i < NX8 + NW8) { in = wi; out = wib; idx = i - NX8; }
    else                    { in = wo; out = wob; idx = i - NX8 - NW8; }
    const float4* p = (const float4*)in;
    float4 a = p[2 * idx], b = p[2 * idx + 1];
    bf16x8 o;
    o[0] = (bf16)a.x; o[1] = (bf16)a.y; o[2] = (bf16)a.z; o[3] = (bf16)a.w;
    o[4] = (bf16)b.x; o[5] = (bf16)b.y; o[6] = (bf16)b.z; o[7] = (bf16)b.w;
    *(bf16x8*)(out + 8 * idx) = o;
}

// ---------------------------------------------------------------------------
// head_mix4: fully LDS-resident head stage with fused c-compute.
// Grid (512, 8): blockIdx.x = 16-row tile (stripes XCDs), blockIdx.y = head.
// Phase 0: stage x-window (bf16), base[h,:K,:], V[h], A[h] into LDS.
// Phase 1: 4 waves compute c for the 16 own rows (butterfly reduce) -> LDS.
// Phase 2: 256 threads = 128 d x 2 subs, T=8 rows each; conv taps all LDS.
// ---------------------------------------------------------------------------
__constant__ int KS_c[8] = {3, 3, 7, 7, 11, 11, 21, 21};

template <int K>
__device__ __forceinline__ void mix_body4(
    int h, int tid, int r0, const bf16* __restrict__ xpb,
    const float* __restrict__ Wc, const float* __restrict__ Aw,
    const float* __restrict__ Vw, const float* __restrict__ basew,
    float alpha, bf16* __restrict__ y,
    bf16* sx, float* sB, float* sV, float* sA, float* sc)
{
    constexpr int T   = 8;
    constexpr int pad = K / 2;
    constexpr int R   = 16 + 2 * pad;    // staged window rows
    constexpr int SX  = R * 16;          // x-window 16B slots
    constexpr int SB  = K * 32;          // base-slab 16B slots (K*128 floats)

    // ---- phase 0: staging ----
    #pragma unroll
    for (int p = 0; p < (SX + 255) / 256; ++p) {
        int slot = p * 256 + tid;
        if (slot < SX) {
            int lrow = slot >> 4;
            int grow = min(max(r0 - pad + lrow, 0), 8191);
            gload_lds16(xpb + (size_t)grow * 1024 + h * 128 + (slot & 15) * 8,
                        sx + slot * 8);
        }
    }
    #pragma unroll
    for (int p = 0; p < (SB + 255) / 256; ++p) {
        int slot = p * 256 + tid;
        if (slot < SB)
            gload_lds16(basew + h * 2688 + slot * 4, sB + slot * 4);
    }
    if (tid < 128) gload_lds16(Vw + h * 512 + tid * 4, sV + tid * 4);
    if (tid < 21)  gload_lds16(Aw + h * 84 + tid * 4, sA + tid * 4);
    __syncthreads();

    // ---- phase 1: fused c-compute. wave w reduces rows 4w..4w+3 ----
    {
        const int wv = tid >> 6, lane = tid & 63;
        #pragma unroll
        for (int q = 0; q < 4; ++q) {
            int lrow = pad + wv * 4 + q;
            float x0 = (float)sx[lrow * 128 + lane];
            float x1 = (float)sx[lrow * 128 + 64 + lane];
            float4 w0 = *(const float4*)(Wc + h * 512 + lane * 4);
            float4 w1 = *(const float4*)(Wc + h * 512 + (64 + lane) * 4);
            float p0 = x0 * w0.x + x1 * w1.x;
            float p1 = x0 * w0.y + x1 * w1.y;
            float p2 = x0 * w0.z + x1 * w1.z;
            float p3 = x0 * w0.w + x1 * w1.w;
            #pragma unroll
            for (int off = 1; off < 64; off <<= 1) {
                p0 += __shfl_xor(p0, off);
                p1 += __shfl_xor(p1, off);
                p2 += __shfl_xor(p2, off);
                p3 += __shfl_xor(p3, off);
            }
            if (lane == 0) {
                sc[(wv * 4 + q) * 4 + 0] = p0;
                sc[(wv * 4 + q) * 4 + 1] = p1;
                sc[(wv * 4 + q) * 4 + 2] = p2;
                sc[(wv * 4 + q) * 4 + 3] = p3;
            }
        }
    }
    __syncthreads();

    // ---- phase 2: conv + mix, all operands from LDS ----
    const int d   = tid & 127;
    const int sub = tid >> 7;
    const int nb  = (r0 & 4095) + sub * 8;   // batch-local first output row

    float w[T + K - 1];
    #pragma unroll
    for (int j = 0; j < T + K - 1; ++j) {
        int nl = nb + j - pad;
        float v = (float)sx[(sub * 8 + j) * 128 + d];
        w[j] = (nl >= 0 && nl < 4096) ? v : 0.f;
    }

    float o[T] = {};
    #pragma unroll
    for (int r = 0; r < 4; ++r) {
        float s[T] = {};
        #pragma unroll
        for (int j = 0; j < K; ++j) {
            float a = sA[r * 21 + j];
            #pragma unroll
            for (int t = 0; t < T; ++t) s[t] += a * w[t + j];
        }
        float vr = sV[r * 128 + d];
        #pragma unroll
        for (int t = 0; t < T; ++t)
            o[t] += (sc[(sub * 8 + t) * 4 + r] * vr) * s[t];
    }

    float tv[T] = {};
    #pragma unroll
    for (int j = 0; j < K; ++j) {
        float bb = sB[j * 128 + d];
        #pragma unroll
        for (int t = 0; t < T; ++t) tv[t] += bb * w[t + j];
    }

    #pragma unroll
    for (int t = 0; t < T; ++t) {
        int rowo = r0 + sub * 8 + t;
        float res = alpha * o[t] + (1.f - alpha) * tv[t];
        y[(size_t)rowo * 1024 + h * 128 + d] = (bf16)res;
    }
}

__global__ __launch_bounds__(256, 4) void head_mix4(
    const bf16* __restrict__ xpb, const float* __restrict__ Wc,
    const float* __restrict__ Aw, const float* __restrict__ Vw,
    const float* __restrict__ basew, const float* __restrict__ alphas,
    bf16* __restrict__ y)
{
    __shared__ __align__(16) bf16  sx[36 * 128];   // 9216 B (max K=21)
    __shared__ __align__(16) float sB[21 * 128];   // 10752 B
    __shared__ __align__(16) float sV[512];        // 2048 B
    __shared__ __align__(16) float sA[84];         // 336 B
    __shared__ float sc[16 * 4];                   // 256 B

    const int h  = blockIdx.y;
    const int r0 = blockIdx.x * 16;
    const float alpha = 1.f / (1.f + __expf(-alphas[h]));

    switch (KS_c[h]) {
        case 3:  mix_body4<3 >(h, threadIdx.x, r0, xpb, Wc, Aw, Vw, basew, alpha, y, sx, sB, sV, sA, sc); break;
        case 7:  mix_body4<7 >(h, threadIdx.x, r0, xpb, Wc, Aw, Vw, basew, alpha, y, sx, sB, sV, sA, sc); break;
        case 11: mix_body4<11>(h, threadIdx.x, r0, xpb, Wc, Aw, Vw, basew, alpha, y, sx, sB, sV, sA, sc); break;
        default: mix_body4<21>(h, threadIdx.x, r0, xpb, Wc, Aw, Vw, basew, alpha, y, sx, sB, sV, sA, sc); break;
    }
}

// ---------------------------------------------------------------------------
extern "C" void kernel_launch(void* const* d_in, const int* in_sizes, int n_in,
                              void* d_out, int out_size, void* d_ws, size_t ws_size,
                              hipStream_t stream)
{
    const float* x      = (const float*)d_in[0];
    const float* W_in   = (const float*)d_in[1];
    const float* b_in   = (const float*)d_in[2];
    const float* W_out  = (const float*)d_in[3];
    const float* b_out  = (const float*)d_in[4];
    const float* Wc     = (const float*)d_in[5];
    const float* Aw     = (const float*)d_in[6];
    const float* Vw     = (const float*)d_in[7];
    const float* basew  = (const float*)d_in[8];
    const float* alphas = (const float*)d_in[9];
    float* out = (float*)d_out;

    const size_t MB = 1u << 20;
    char* ws = (char*)d_ws;
    bf16*  xb   = (bf16*) (ws);             // 16 MB: x bf16
    bf16*  wib  = (bf16*) (ws + 16 * MB);   //  2 MB: W_in bf16
    bf16*  wob  = (bf16*) (ws + 18 * MB);   //  2 MB: W_out bf16
    bf16*  xpb  = (bf16*) (ws + 20 * MB);   // 16 MB: x_proj bf16
    bf16*  yb   = (bf16*) (ws + 36 * MB);   // 16 MB: head-concat y bf16

    const int NTOT8 = (2 * 4096 * 1024 + 2 * 1024 * 1024) / 8;

    cast_all_kernel<<<NTOT8 / 256, 256, 0, stream>>>(x, xb, W_in, wib, W_out, wob);

    gemm_nt<bf16><<<dim3(8192 / BM, 1024 / BN), 256, 0, stream>>>(
        xb, wib, b_in, xpb, 8192, 1024, 1024);

    head_mix4<<<dim3(512, 8), 256, 0, stream>>>(
        xpb, Wc, Aw, Vw, basew, alphas, yb);

    gemm_nt<float><<<dim3(8192 / BM, 1024 / BN), 256, 0, stream>>>(
        yb, wob, b_out, out, 8192, 1024, 1024);
}

// Round 7
// 182.315 us; speedup vs baseline: 1.3280x; 1.3280x over previous
//
#include <hip/hip_runtime.h>
#include <stdint.h>

typedef __bf16 bf16;
typedef __bf16 bf16x8 __attribute__((ext_vector_type(8)));
typedef float f32x4 __attribute__((ext_vector_type(4)));

#define AS1 __attribute__((address_space(1)))
#define AS3 __attribute__((address_space(3)))

__device__ __forceinline__ void gload_lds16(const void* g, void* l) {
    __builtin_amdgcn_global_load_lds((const AS1 uint32_t*)g, (AS3 uint32_t*)l, 16, 0, 0);
}

// ---------------------------------------------------------------------------
// NT GEMM: C[m,n] = sum_k A[m,k]*B[n,k] + bias[n]  (exact R5 version)
// BM=128, BN=64, BK=64 -> grid 64x16 = 1024 blocks = 4 blocks/CU.
// ---------------------------------------------------------------------------
#define BM 128
#define BN 64
#define BK 64

template <typename OT>
__global__ __launch_bounds__(256, 4) void gemm_nt(
    const bf16* __restrict__ A, const bf16* __restrict__ B,
    const float* __restrict__ bias, OT* __restrict__ C,
    int M, int N, int K)
{
    __shared__ bf16 smA[BM * BK];   // 16 KB
    __shared__ bf16 smB[BN * BK];   //  8 KB

    const int tid  = threadIdx.x;
    const int wave = tid >> 6;
    const int lane = tid & 63;
    const int wm = (wave >> 1) * 64;
    const int wn = (wave & 1) * 32;
    const int rowA0 = blockIdx.x * BM;
    const int rowB0 = blockIdx.y * BN;

    f32x4 acc[4][2] = {};

    const int g  = lane >> 4;
    const int rm = lane & 15;

    for (int k0 = 0; k0 < K; k0 += BK) {
        #pragma unroll
        for (int i = 0; i < 4; ++i) {
            int slot = i * 256 + tid;
            int row  = slot >> 3;
            int kg   = slot & 7;
            int kd   = kg ^ ((row >> 1) & 7);
            gload_lds16(A + (size_t)(rowA0 + row) * K + k0 + kd * 8, &smA[slot * 8]);
        }
        #pragma unroll
        for (int i = 0; i < 2; ++i) {
            int slot = i * 256 + tid;
            int row  = slot >> 3;
            int kg   = slot & 7;
            int kd   = kg ^ ((row >> 1) & 7);
            gload_lds16(B + (size_t)(rowB0 + row) * K + k0 + kd * 8, &smB[slot * 8]);
        }
        __syncthreads();

        #pragma unroll
        for (int s = 0; s < 2; ++s) {
            bf16x8 af[4], bfr[2];
            #pragma unroll
            for (int mi = 0; mi < 4; ++mi) {
                int row  = wm + mi * 16 + rm;
                int slot = row * 8 + ((s * 4 + g) ^ ((row >> 1) & 7));
                af[mi] = *(const bf16x8*)&smA[slot * 8];
            }
            #pragma unroll
            for (int ni = 0; ni < 2; ++ni) {
                int row  = wn + ni * 16 + rm;
                int slot = row * 8 + ((s * 4 + g) ^ ((row >> 1) & 7));
                bfr[ni] = *(const bf16x8*)&smB[slot * 8];
            }
            #pragma unroll
            for (int mi = 0; mi < 4; ++mi)
                #pragma unroll
                for (int ni = 0; ni < 2; ++ni)
                    acc[mi][ni] = __builtin_amdgcn_mfma_f32_16x16x32_bf16(
                        af[mi], bfr[ni], acc[mi][ni], 0, 0, 0);
        }
        __syncthreads();
    }

    const int quad = lane >> 4;
    #pragma unroll
    for (int ni = 0; ni < 2; ++ni) {
        int col = rowB0 + wn + ni * 16 + rm;
        float bcol = bias[col];
        #pragma unroll
        for (int mi = 0; mi < 4; ++mi) {
            #pragma unroll
            for (int r = 0; r < 4; ++r) {
                int rowc = rowA0 + wm + mi * 16 + quad * 4 + r;
                C[(size_t)rowc * N + col] = (OT)(acc[mi][ni][r] + bcol);
            }
        }
    }
}

// ---------------------------------------------------------------------------
// fused fp32 -> bf16 cast of x, W_in, W_out (one launch)
// ---------------------------------------------------------------------------
__global__ void cast_all_kernel(const float* __restrict__ x, bf16* __restrict__ xb,
                                const float* __restrict__ wi, bf16* __restrict__ wib,
                                const float* __restrict__ wo, bf16* __restrict__ wob)
{
    const int NX8 = (2 * 4096 * 1024) / 8;
    const int NW8 = (1024 * 1024) / 8;
    int i = blockIdx.x * 256 + threadIdx.x;
    const float* in; bf16* out; int idx;
    if (i < NX8)            { in = x;  out = xb;  idx = i; }
    else if (i < NX8 + NW8) { in = wi; out = wib; idx = i - NX8; }
    else                    { in = wo; out = wob; idx = i - NX8 - NW8; }
    const float4* p = (const float4*)in;
    float4 a = p[2 * idx], b = p[2 * idx + 1];
    bf16x8 o;
    o[0] = (bf16)a.x; o[1] = (bf16)a.y; o[2] = (bf16)a.z; o[3] = (bf16)a.w;
    o[4] = (bf16)b.x; o[5] = (bf16)b.y; o[6] = (bf16)b.z; o[7] = (bf16)b.w;
    *(bf16x8*)(out + 8 * idx) = o;
}

// ---------------------------------------------------------------------------
// c_compute: c[row,h,r] = sum_d xpb[row, h*128+d] * Wc[h,d,r]  (exact R5)
// ---------------------------------------------------------------------------
__global__ __launch_bounds__(256) void c_compute(
    const bf16* __restrict__ xpb, const float* __restrict__ Wc,
    float* __restrict__ cbuf)
{
    const int wave = threadIdx.x >> 6, lane = threadIdx.x & 63;
    const int row  = blockIdx.x * 4 + wave;
    const int h    = lane >> 3;
    const int d0   = (lane & 7) * 16;

    const bf16* xr = xpb + (size_t)row * 1024 + lane * 16;
    bf16x8 v0 = *(const bf16x8*)xr;
    bf16x8 v1 = *(const bf16x8*)(xr + 8);
    float p0 = 0.f, p1 = 0.f, p2 = 0.f, p3 = 0.f;
    #pragma unroll
    for (int i = 0; i < 16; ++i) {
        float xv = (i < 8) ? (float)v0[i & 7] : (float)v1[i & 7];
        float4 wr = *(const float4*)(Wc + h * 512 + (d0 + i) * 4);
        p0 += xv * wr.x; p1 += xv * wr.y; p2 += xv * wr.z; p3 += xv * wr.w;
    }
    #pragma unroll
    for (int off = 1; off <= 4; off <<= 1) {
        p0 += __shfl_xor(p0, off);
        p1 += __shfl_xor(p1, off);
        p2 += __shfl_xor(p2, off);
        p3 += __shfl_xor(p3, off);
    }
    if ((lane & 7) == 0) {
        float4 o = {p0, p1, p2, p3};
        *(float4*)(cbuf + (size_t)row * 32 + h * 4) = o;
    }
}

// ---------------------------------------------------------------------------
// head_mix5: R5's head_mix3 + LDS-staged base slab (the ONLY per-thread
// in-loop global load in R5). Everything else kept identical to the proven
// 42 us version: A-taps are block-uniform (s_load), V/cbuf post-loop.
// Grid (512, 8): blockIdx.x = 16-row tile (XCD-balanced), blockIdx.y = head.
// ---------------------------------------------------------------------------
__constant__ int KS_c[8] = {3, 3, 7, 7, 11, 11, 21, 21};

template <int K>
__device__ __forceinline__ void mix_body5(
    int h, int tid, int r0, const bf16* __restrict__ xpb,
    const float* __restrict__ cbuf, const float* __restrict__ Aw,
    const float* __restrict__ Vw, const float* __restrict__ basew,
    float alpha, bf16* __restrict__ y, bf16* sx, float* sB)
{
    constexpr int T   = 8;
    constexpr int pad = K / 2;
    constexpr int R   = 16 + 2 * pad;    // staged window rows
    constexpr int SX  = R * 16;          // x-window 16B slots
    constexpr int SB  = K * 32;          // base-slab 16B slots

    // ---- stage x-window (bf16) and base[h,:K,:] (fp32) into LDS ----
    #pragma unroll
    for (int p = 0; p < (SX + 255) / 256; ++p) {
        int slot = p * 256 + tid;
        if (slot < SX) {
            int lrow = slot >> 4;
            int grow = min(max(r0 - pad + lrow, 0), 8191);
            gload_lds16(xpb + (size_t)grow * 1024 + h * 128 + (slot & 15) * 8,
                        sx + slot * 8);
        }
    }
    #pragma unroll
    for (int p = 0; p < (SB + 255) / 256; ++p) {
        int slot = p * 256 + tid;
        if (slot < SB)
            gload_lds16(basew + h * 2688 + slot * 4, sB + slot * 4);
    }
    __syncthreads();

    const int d   = tid & 127;
    const int sub = tid >> 7;
    const int lr0 = sub * 8;
    const int nb  = (r0 & 4095) + sub * 8;   // batch-local first output row

    float w[T + K - 1];
    #pragma unroll
    for (int j = 0; j < T + K - 1; ++j) {
        int nl = nb + j - pad;
        float v = (float)sx[(lr0 + j) * 128 + d];
        w[j] = (nl >= 0 && nl < 4096) ? v : 0.f;
    }

    float s0[T] = {}, s1[T] = {}, s2[T] = {}, s3[T] = {}, tv[T] = {};
    const float* Ah = Aw + h * 84;
    #pragma unroll
    for (int j = 0; j < K; ++j) {
        float a0 = Ah[j], a1 = Ah[21 + j], a2 = Ah[42 + j], a3 = Ah[63 + j];
        float bbj = sB[j * 128 + d];
        #pragma unroll
        for (int t = 0; t < T; ++t) {
            float x = w[t + j];
            s0[t] += a0 * x; s1[t] += a1 * x;
            s2[t] += a2 * x; s3[t] += a3 * x;
            tv[t] += bbj * x;
        }
    }

    float v0 = Vw[h * 512 + d],       v1 = Vw[h * 512 + 128 + d];
    float v2 = Vw[h * 512 + 256 + d], v3 = Vw[h * 512 + 384 + d];
    #pragma unroll
    for (int t = 0; t < T; ++t) {
        int rowo = r0 + sub * 8 + t;
        float4 c4 = *(const float4*)(cbuf + (size_t)rowo * 32 + h * 4);
        float o = alpha * (c4.x * v0 * s0[t] + c4.y * v1 * s1[t] +
                           c4.z * v2 * s2[t] + c4.w * v3 * s3[t])
                + (1.f - alpha) * tv[t];
        y[(size_t)rowo * 1024 + h * 128 + d] = (bf16)o;
    }
}

__global__ __launch_bounds__(256, 4) void head_mix5(
    const bf16* __restrict__ xpb, const float* __restrict__ cbuf,
    const float* __restrict__ Aw, const float* __restrict__ Vw,
    const float* __restrict__ basew, const float* __restrict__ alphas,
    bf16* __restrict__ y)
{
    __shared__ __align__(16) bf16  sx[36 * 128];   // 9216 B (max K=21)
    __shared__ __align__(16) float sB[21 * 128];   // 10752 B
    const int h  = blockIdx.y;
    const int r0 = blockIdx.x * 16;
    const float alpha = 1.f / (1.f + __expf(-alphas[h]));

    switch (KS_c[h]) {
        case 3:  mix_body5<3 >(h, threadIdx.x, r0, xpb, cbuf, Aw, Vw, basew, alpha, y, sx, sB); break;
        case 7:  mix_body5<7 >(h, threadIdx.x, r0, xpb, cbuf, Aw, Vw, basew, alpha, y, sx, sB); break;
        case 11: mix_body5<11>(h, threadIdx.x, r0, xpb, cbuf, Aw, Vw, basew, alpha, y, sx, sB); break;
        default: mix_body5<21>(h, threadIdx.x, r0, xpb, cbuf, Aw, Vw, basew, alpha, y, sx, sB); break;
    }
}

// ---------------------------------------------------------------------------
extern "C" void kernel_launch(void* const* d_in, const int* in_sizes, int n_in,
                              void* d_out, int out_size, void* d_ws, size_t ws_size,
                              hipStream_t stream)
{
    const float* x      = (const float*)d_in[0];
    const float* W_in   = (const float*)d_in[1];
    const float* b_in   = (const float*)d_in[2];
    const float* W_out  = (const float*)d_in[3];
    const float* b_out  = (const float*)d_in[4];
    const float* Wc     = (const float*)d_in[5];
    const float* Aw     = (const float*)d_in[6];
    const float* Vw     = (const float*)d_in[7];
    const float* basew  = (const float*)d_in[8];
    const float* alphas = (const float*)d_in[9];
    float* out = (float*)d_out;

    const size_t MB = 1u << 20;
    char* ws = (char*)d_ws;
    bf16*  xb   = (bf16*) (ws);             // 16 MB: x bf16
    bf16*  wib  = (bf16*) (ws + 16 * MB);   //  2 MB: W_in bf16
    bf16*  wob  = (bf16*) (ws + 18 * MB);   //  2 MB: W_out bf16
    bf16*  xpb  = (bf16*) (ws + 20 * MB);   // 16 MB: x_proj bf16
    bf16*  yb   = (bf16*) (ws + 36 * MB);   // 16 MB: head-concat y bf16
    float* cbuf = (float*)(ws + 52 * MB);   //  1 MB: c coefficients

    const int NTOT8 = (2 * 4096 * 1024 + 2 * 1024 * 1024) / 8;

    cast_all_kernel<<<NTOT8 / 256, 256, 0, stream>>>(x, xb, W_in, wib, W_out, wob);

    gemm_nt<bf16><<<dim3(8192 / BM, 1024 / BN), 256, 0, stream>>>(
        xb, wib, b_in, xpb, 8192, 1024, 1024);

    c_compute<<<8192 / 4, 256, 0, stream>>>(xpb, Wc, cbuf);

    head_mix5<<<dim3(512, 8), 256, 0, stream>>>(
        xpb, cbuf, Aw, Vw, basew, alphas, yb);

    gemm_nt<float><<<dim3(8192 / BM, 1024 / BN), 256, 0, stream>>>(
        yb, wob, b_out, out, 8192, 1024, 1024);
}

// Round 8
// 179.839 us; speedup vs baseline: 1.3463x; 1.0138x over previous
//
#include <hip/hip_runtime.h>
#include <stdint.h>

typedef __bf16 bf16;
typedef __bf16 bf16x8 __attribute__((ext_vector_type(8)));
typedef float f32x4 __attribute__((ext_vector_type(4)));
typedef float f32x16 __attribute__((ext_vector_type(16)));

#define AS1 __attribute__((address_space(1)))
#define AS3 __attribute__((address_space(3)))

__device__ __forceinline__ void gload_lds16(const void* g, void* l) {
    __builtin_amdgcn_global_load_lds((const AS1 uint32_t*)g, (AS3 uint32_t*)l, 16, 0, 0);
}

// ---------------------------------------------------------------------------
// NT GEMM via 32x32x16 MFMA: C[m,n] = sum_k A[m,k]*B[n,k] + bias[n].
// BM=128, BN=128, BK=64 -> grid (64,8) = 512 blocks = 2/CU.
// 4 waves in 2x2; wave tile 64x64 = 2x2 MFMAs of 32x32 (acc 4x16 f32).
// Same staging/swizzle family as R5: 8 k-groups/row, kd = kg^((row>>1)&7)
// -> fragment ds_read_b128 is 2-way bank aliased (free, m136).
// blockIdx.x = M tile: blocks sharing an A tile land on one XCD.
// ---------------------------------------------------------------------------
#define BM 128
#define BN 128
#define BK 64

template <typename OT>
__global__ __launch_bounds__(256, 2) void gemm_nt(
    const bf16* __restrict__ A, const bf16* __restrict__ B,
    const float* __restrict__ bias, OT* __restrict__ C,
    int M, int N, int K)
{
    __shared__ bf16 smA[BM * BK];   // 16 KB
    __shared__ bf16 smB[BN * BK];   // 16 KB

    const int tid  = threadIdx.x;
    const int wave = tid >> 6;
    const int lane = tid & 63;
    const int wm = (wave >> 1) * 64;   // 0,64
    const int wn = (wave & 1) * 64;    // 0,64
    const int rowA0 = blockIdx.x * BM;
    const int rowB0 = blockIdx.y * BN;

    f32x16 acc[2][2] = {};

    const int l31 = lane & 31;
    const int khi = lane >> 5;         // 0,1: k-subgroup within a k-step

    for (int k0 = 0; k0 < K; k0 += BK) {
        // ---- stage A,B tiles: 4 issues each of 256 lanes x 16B ----
        #pragma unroll
        for (int i = 0; i < 4; ++i) {
            int slot = i * 256 + tid;          // 1024 slots of 16B per tile
            int row  = slot >> 3;              // 0..127
            int kg   = slot & 7;
            int kd   = kg ^ ((row >> 1) & 7);
            gload_lds16(A + (size_t)(rowA0 + row) * K + k0 + kd * 8, &smA[slot * 8]);
            gload_lds16(B + (size_t)(rowB0 + row) * K + k0 + kd * 8, &smB[slot * 8]);
        }
        __syncthreads();

        // ---- 4 k-steps of 16 ----
        #pragma unroll
        for (int s = 0; s < 4; ++s) {
            bf16x8 af[2], bfr[2];
            #pragma unroll
            for (int mi = 0; mi < 2; ++mi) {
                int row  = wm + mi * 32 + l31;
                int slot = row * 8 + ((s * 2 + khi) ^ ((row >> 1) & 7));
                af[mi] = *(const bf16x8*)&smA[slot * 8];
            }
            #pragma unroll
            for (int ni = 0; ni < 2; ++ni) {
                int row  = wn + ni * 32 + l31;
                int slot = row * 8 + ((s * 2 + khi) ^ ((row >> 1) & 7));
                bfr[ni] = *(const bf16x8*)&smB[slot * 8];
            }
            #pragma unroll
            for (int mi = 0; mi < 2; ++mi)
                #pragma unroll
                for (int ni = 0; ni < 2; ++ni)
                    acc[mi][ni] = __builtin_amdgcn_mfma_f32_32x32x16_bf16(
                        af[mi], bfr[ni], acc[mi][ni], 0, 0, 0);
        }
        __syncthreads();
    }

    // ---- epilogue: 32x32 C/D layout col=lane&31,
    //      row = (reg&3) + 8*(reg>>2) + 4*(lane>>5) ----
    #pragma unroll
    for (int ni = 0; ni < 2; ++ni) {
        int col = rowB0 + wn + ni * 32 + l31;
        float bcol = bias[col];
        #pragma unroll
        for (int mi = 0; mi < 2; ++mi) {
            #pragma unroll
            for (int r = 0; r < 16; ++r) {
                int row32 = (r & 3) + 8 * (r >> 2) + 4 * khi;
                int rowc  = rowA0 + wm + mi * 32 + row32;
                C[(size_t)rowc * N + col] = (OT)(acc[mi][ni][r] + bcol);
            }
        }
    }
}

// ---------------------------------------------------------------------------
// fused fp32 -> bf16 cast of x, W_in, W_out (one launch)
// ---------------------------------------------------------------------------
__global__ void cast_all_kernel(const float* __restrict__ x, bf16* __restrict__ xb,
                                const float* __restrict__ wi, bf16* __restrict__ wib,
                                const float* __restrict__ wo, bf16* __restrict__ wob)
{
    const int NX8 = (2 * 4096 * 1024) / 8;
    const int NW8 = (1024 * 1024) / 8;
    int i = blockIdx.x * 256 + threadIdx.x;
    const float* in; bf16* out; int idx;
    if (i < NX8)            { in = x;  out = xb;  idx = i; }
    else if (i < NX8 + NW8) { in = wi; out = wib; idx = i - NX8; }
    else                    { in = wo; out = wob; idx = i - NX8 - NW8; }
    const float4* p = (const float4*)in;
    float4 a = p[2 * idx], b = p[2 * idx + 1];
    bf16x8 o;
    o[0] = (bf16)a.x; o[1] = (bf16)a.y; o[2] = (bf16)a.z; o[3] = (bf16)a.w;
    o[4] = (bf16)b.x; o[5] = (bf16)b.y; o[6] = (bf16)b.z; o[7] = (bf16)b.w;
    *(bf16x8*)(out + 8 * idx) = o;
}

// ---------------------------------------------------------------------------
// c_compute: c[row,h,r] = sum_d xpb[row, h*128+d] * Wc[h,d,r]  (exact R5)
// ---------------------------------------------------------------------------
__global__ __launch_bounds__(256) void c_compute(
    const bf16* __restrict__ xpb, const float* __restrict__ Wc,
    float* __restrict__ cbuf)
{
    const int wave = threadIdx.x >> 6, lane = threadIdx.x & 63;
    const int row  = blockIdx.x * 4 + wave;
    const int h    = lane >> 3;
    const int d0   = (lane & 7) * 16;

    const bf16* xr = xpb + (size_t)row * 1024 + lane * 16;
    bf16x8 v0 = *(const bf16x8*)xr;
    bf16x8 v1 = *(const bf16x8*)(xr + 8);
    float p0 = 0.f, p1 = 0.f, p2 = 0.f, p3 = 0.f;
    #pragma unroll
    for (int i = 0; i < 16; ++i) {
        float xv = (i < 8) ? (float)v0[i & 7] : (float)v1[i & 7];
        float4 wr = *(const float4*)(Wc + h * 512 + (d0 + i) * 4);
        p0 += xv * wr.x; p1 += xv * wr.y; p2 += xv * wr.z; p3 += xv * wr.w;
    }
    #pragma unroll
    for (int off = 1; off <= 4; off <<= 1) {
        p0 += __shfl_xor(p0, off);
        p1 += __shfl_xor(p1, off);
        p2 += __shfl_xor(p2, off);
        p3 += __shfl_xor(p3, off);
    }
    if ((lane & 7) == 0) {
        float4 o = {p0, p1, p2, p3};
        *(float4*)(cbuf + (size_t)row * 32 + h * 4) = o;
    }
}

// ---------------------------------------------------------------------------
// head_mix5 (unchanged from R7): LDS-staged x-window + base slab.
// Grid (512, 8): blockIdx.x = 16-row tile (XCD-balanced), blockIdx.y = head.
// ---------------------------------------------------------------------------
__constant__ int KS_c[8] = {3, 3, 7, 7, 11, 11, 21, 21};

template <int K>
__device__ __forceinline__ void mix_body5(
    int h, int tid, int r0, const bf16* __restrict__ xpb,
    const float* __restrict__ cbuf, const float* __restrict__ Aw,
    const float* __restrict__ Vw, const float* __restrict__ basew,
    float alpha, bf16* __restrict__ y, bf16* sx, float* sB)
{
    constexpr int T   = 8;
    constexpr int pad = K / 2;
    constexpr int R   = 16 + 2 * pad;
    constexpr int SX  = R * 16;
    constexpr int SB  = K * 32;

    #pragma unroll
    for (int p = 0; p < (SX + 255) / 256; ++p) {
        int slot = p * 256 + tid;
        if (slot < SX) {
            int lrow = slot >> 4;
            int grow = min(max(r0 - pad + lrow, 0), 8191);
            gload_lds16(xpb + (size_t)grow * 1024 + h * 128 + (slot & 15) * 8,
                        sx + slot * 8);
        }
    }
    #pragma unroll
    for (int p = 0; p < (SB + 255) / 256; ++p) {
        int slot = p * 256 + tid;
        if (slot < SB)
            gload_lds16(basew + h * 2688 + slot * 4, sB + slot * 4);
    }
    __syncthreads();

    const int d   = tid & 127;
    const int sub = tid >> 7;
    const int lr0 = sub * 8;
    const int nb  = (r0 & 4095) + sub * 8;

    float w[T + K - 1];
    #pragma unroll
    for (int j = 0; j < T + K - 1; ++j) {
        int nl = nb + j - pad;
        float v = (float)sx[(lr0 + j) * 128 + d];
        w[j] = (nl >= 0 && nl < 4096) ? v : 0.f;
    }

    float s0[T] = {}, s1[T] = {}, s2[T] = {}, s3[T] = {}, tv[T] = {};
    const float* Ah = Aw + h * 84;
    #pragma unroll
    for (int j = 0; j < K; ++j) {
        float a0 = Ah[j], a1 = Ah[21 + j], a2 = Ah[42 + j], a3 = Ah[63 + j];
        float bbj = sB[j * 128 + d];
        #pragma unroll
        for (int t = 0; t < T; ++t) {
            float x = w[t + j];
            s0[t] += a0 * x; s1[t] += a1 * x;
            s2[t] += a2 * x; s3[t] += a3 * x;
            tv[t] += bbj * x;
        }
    }

    float v0 = Vw[h * 512 + d],       v1 = Vw[h * 512 + 128 + d];
    float v2 = Vw[h * 512 + 256 + d], v3 = Vw[h * 512 + 384 + d];
    #pragma unroll
    for (int t = 0; t < T; ++t) {
        int rowo = r0 + sub * 8 + t;
        float4 c4 = *(const float4*)(cbuf + (size_t)rowo * 32 + h * 4);
        float o = alpha * (c4.x * v0 * s0[t] + c4.y * v1 * s1[t] +
                           c4.z * v2 * s2[t] + c4.w * v3 * s3[t])
                + (1.f - alpha) * tv[t];
        y[(size_t)rowo * 1024 + h * 128 + d] = (bf16)o;
    }
}

__global__ __launch_bounds__(256, 4) void head_mix5(
    const bf16* __restrict__ xpb, const float* __restrict__ cbuf,
    const float* __restrict__ Aw, const float* __restrict__ Vw,
    const float* __restrict__ basew, const float* __restrict__ alphas,
    bf16* __restrict__ y)
{
    __shared__ __align__(16) bf16  sx[36 * 128];
    __shared__ __align__(16) float sB[21 * 128];
    const int h  = blockIdx.y;
    const int r0 = blockIdx.x * 16;
    const float alpha = 1.f / (1.f + __expf(-alphas[h]));

    switch (KS_c[h]) {
        case 3:  mix_body5<3 >(h, threadIdx.x, r0, xpb, cbuf, Aw, Vw, basew, alpha, y, sx, sB); break;
        case 7:  mix_body5<7 >(h, threadIdx.x, r0, xpb, cbuf, Aw, Vw, basew, alpha, y, sx, sB); break;
        case 11: mix_body5<11>(h, threadIdx.x, r0, xpb, cbuf, Aw, Vw, basew, alpha, y, sx, sB); break;
        default: mix_body5<21>(h, threadIdx.x, r0, xpb, cbuf, Aw, Vw, basew, alpha, y, sx, sB); break;
    }
}

// ---------------------------------------------------------------------------
extern "C" void kernel_launch(void* const* d_in, const int* in_sizes, int n_in,
                              void* d_out, int out_size, void* d_ws, size_t ws_size,
                              hipStream_t stream)
{
    const float* x      = (const float*)d_in[0];
    const float* W_in   = (const float*)d_in[1];
    const float* b_in   = (const float*)d_in[2];
    const float* W_out  = (const float*)d_in[3];
    const float* b_out  = (const float*)d_in[4];
    const float* Wc     = (const float*)d_in[5];
    const float* Aw     = (const float*)d_in[6];
    const float* Vw     = (const float*)d_in[7];
    const float* basew  = (const float*)d_in[8];
    const float* alphas = (const float*)d_in[9];
    float* out = (float*)d_out;

    const size_t MB = 1u << 20;
    char* ws = (char*)d_ws;
    bf16*  xb   = (bf16*) (ws);             // 16 MB: x bf16
    bf16*  wib  = (bf16*) (ws + 16 * MB);   //  2 MB: W_in bf16
    bf16*  wob  = (bf16*) (ws + 18 * MB);   //  2 MB: W_out bf16
    bf16*  xpb  = (bf16*) (ws + 20 * MB);   // 16 MB: x_proj bf16
    bf16*  yb   = (bf16*) (ws + 36 * MB);   // 16 MB: head-concat y bf16
    float* cbuf = (float*)(ws + 52 * MB);   //  1 MB: c coefficients

    const int NTOT8 = (2 * 4096 * 1024 + 2 * 1024 * 1024) / 8;

    cast_all_kernel<<<NTOT8 / 256, 256, 0, stream>>>(x, xb, W_in, wib, W_out, wob);

    gemm_nt<bf16><<<dim3(8192 / BM, 1024 / BN), 256, 0, stream>>>(
        xb, wib, b_in, xpb, 8192, 1024, 1024);

    c_compute<<<8192 / 4, 256, 0, stream>>>(xpb, Wc, cbuf);

    head_mix5<<<dim3(512, 8), 256, 0, stream>>>(
        xpb, cbuf, Aw, Vw, basew, alphas, yb);

    gemm_nt<float><<<dim3(8192 / BM, 1024 / BN), 256, 0, stream>>>(
        yb, wob, b_out, out, 8192, 1024, 1024);
}

// Round 9
// 172.475 us; speedup vs baseline: 1.4038x; 1.0427x over previous
//
#include <hip/hip_runtime.h>
#include <stdint.h>

typedef __bf16 bf16;
typedef __bf16 bf16x8 __attribute__((ext_vector_type(8)));
typedef float f32x4 __attribute__((ext_vector_type(4)));
typedef float f32x16 __attribute__((ext_vector_type(16)));

#define AS1 __attribute__((address_space(1)))
#define AS3 __attribute__((address_space(3)))

__device__ __forceinline__ void gload_lds16(const void* g, void* l) {
    __builtin_amdgcn_global_load_lds((const AS1 uint32_t*)g, (AS3 uint32_t*)l, 16, 0, 0);
}

// ---------------------------------------------------------------------------
// NT GEMM via 32x32x16 MFMA: C[m,n] = sum_k A[m,k]*B[n,k] + bias[n].
// BM=BN=128, BK=128 -> K=1024 in 8 iterations (half the barrier drains of
// BK=64). LDS 2x32 KB = 64 KB, still 2 blocks/CU (no occupancy change).
// Swizzle: 16 k-groups/row, kd = kg^((row>>1)&15) -> quarter-wave fragment
// reads hit 2 lanes per bank-quad (free, m136).
// blockIdx.x = M tile: blocks sharing an A tile land on one XCD.
// ---------------------------------------------------------------------------
#define BM 128
#define BN 128
#define BK 128

template <typename OT>
__global__ __launch_bounds__(256, 2) void gemm_nt(
    const bf16* __restrict__ A, const bf16* __restrict__ B,
    const float* __restrict__ bias, OT* __restrict__ C,
    int M, int N, int K)
{
    __shared__ bf16 smA[BM * BK];   // 32 KB
    __shared__ bf16 smB[BN * BK];   // 32 KB

    const int tid  = threadIdx.x;
    const int wave = tid >> 6;
    const int lane = tid & 63;
    const int wm = (wave >> 1) * 64;   // 0,64
    const int wn = (wave & 1) * 64;    // 0,64
    const int rowA0 = blockIdx.x * BM;
    const int rowB0 = blockIdx.y * BN;

    f32x16 acc[2][2] = {};

    const int l31 = lane & 31;
    const int khi = lane >> 5;         // 0,1: k-half within a k-step

    for (int k0 = 0; k0 < K; k0 += BK) {
        // ---- stage A,B tiles: 8 issues each of 256 lanes x 16B ----
        #pragma unroll
        for (int i = 0; i < 8; ++i) {
            int slot = i * 256 + tid;          // 2048 slots of 16B per tile
            int row  = slot >> 4;              // 0..127
            int kg   = slot & 15;
            int kd   = kg ^ ((row >> 1) & 15);
            gload_lds16(A + (size_t)(rowA0 + row) * K + k0 + kd * 8, &smA[slot * 8]);
            gload_lds16(B + (size_t)(rowB0 + row) * K + k0 + kd * 8, &smB[slot * 8]);
        }
        __syncthreads();

        // ---- 8 k-steps of 16 ----
        #pragma unroll
        for (int s = 0; s < 8; ++s) {
            bf16x8 af[2], bfr[2];
            #pragma unroll
            for (int mi = 0; mi < 2; ++mi) {
                int row  = wm + mi * 32 + l31;
                int slot = row * 16 + ((s * 2 + khi) ^ ((row >> 1) & 15));
                af[mi] = *(const bf16x8*)&smA[slot * 8];
            }
            #pragma unroll
            for (int ni = 0; ni < 2; ++ni) {
                int row  = wn + ni * 32 + l31;
                int slot = row * 16 + ((s * 2 + khi) ^ ((row >> 1) & 15));
                bfr[ni] = *(const bf16x8*)&smB[slot * 8];
            }
            #pragma unroll
            for (int mi = 0; mi < 2; ++mi)
                #pragma unroll
                for (int ni = 0; ni < 2; ++ni)
                    acc[mi][ni] = __builtin_amdgcn_mfma_f32_32x32x16_bf16(
                        af[mi], bfr[ni], acc[mi][ni], 0, 0, 0);
        }
        __syncthreads();
    }

    // ---- epilogue: 32x32 C/D layout col=lane&31,
    //      row = (reg&3) + 8*(reg>>2) + 4*(lane>>5) ----
    #pragma unroll
    for (int ni = 0; ni < 2; ++ni) {
        int col = rowB0 + wn + ni * 32 + l31;
        float bcol = bias[col];
        #pragma unroll
        for (int mi = 0; mi < 2; ++mi) {
            #pragma unroll
            for (int r = 0; r < 16; ++r) {
                int row32 = (r & 3) + 8 * (r >> 2) + 4 * khi;
                int rowc  = rowA0 + wm + mi * 32 + row32;
                C[(size_t)rowc * N + col] = (OT)(acc[mi][ni][r] + bcol);
            }
        }
    }
}

// ---------------------------------------------------------------------------
// fused fp32 -> bf16 cast of x, W_in, W_out (one launch)
// ---------------------------------------------------------------------------
__global__ void cast_all_kernel(const float* __restrict__ x, bf16* __restrict__ xb,
                                const float* __restrict__ wi, bf16* __restrict__ wib,
                                const float* __restrict__ wo, bf16* __restrict__ wob)
{
    const int NX8 = (2 * 4096 * 1024) / 8;
    const int NW8 = (1024 * 1024) / 8;
    int i = blockIdx.x * 256 + threadIdx.x;
    const float* in; bf16* out; int idx;
    if (i < NX8)            { in = x;  out = xb;  idx = i; }
    else if (i < NX8 + NW8) { in = wi; out = wib; idx = i - NX8; }
    else                    { in = wo; out = wob; idx = i - NX8 - NW8; }
    const float4* p = (const float4*)in;
    float4 a = p[2 * idx], b = p[2 * idx + 1];
    bf16x8 o;
    o[0] = (bf16)a.x; o[1] = (bf16)a.y; o[2] = (bf16)a.z; o[3] = (bf16)a.w;
    o[4] = (bf16)b.x; o[5] = (bf16)b.y; o[6] = (bf16)b.z; o[7] = (bf16)b.w;
    *(bf16x8*)(out + 8 * idx) = o;
}

// ---------------------------------------------------------------------------
// head_mix6: R7's head_mix5 + fused c-compute (phase 1, transient regs only;
// phase 2 kept byte-identical to the proven no-spill structure, cbuf -> sc).
// Grid (512, 8): blockIdx.x = 16-row tile (XCD-balanced), blockIdx.y = head.
// ---------------------------------------------------------------------------
__constant__ int KS_c[8] = {3, 3, 7, 7, 11, 11, 21, 21};

template <int K>
__device__ __forceinline__ void mix_body6(
    int h, int tid, int r0, const bf16* __restrict__ xpb,
    const float* __restrict__ Wc, const float* __restrict__ Aw,
    const float* __restrict__ Vw, const float* __restrict__ basew,
    float alpha, bf16* __restrict__ y, bf16* sx, float* sB, float* sc)
{
    constexpr int T   = 8;
    constexpr int pad = K / 2;
    constexpr int R   = 16 + 2 * pad;
    constexpr int SX  = R * 16;
    constexpr int SB  = K * 32;

    // ---- stage x-window (bf16) and base[h,:K,:] (fp32) into LDS ----
    #pragma unroll
    for (int p = 0; p < (SX + 255) / 256; ++p) {
        int slot = p * 256 + tid;
        if (slot < SX) {
            int lrow = slot >> 4;
            int grow = min(max(r0 - pad + lrow, 0), 8191);
            gload_lds16(xpb + (size_t)grow * 1024 + h * 128 + (slot & 15) * 8,
                        sx + slot * 8);
        }
    }
    #pragma unroll
    for (int p = 0; p < (SB + 255) / 256; ++p) {
        int slot = p * 256 + tid;
        if (slot < SB)
            gload_lds16(basew + h * 2688 + slot * 4, sB + slot * 4);
    }
    __syncthreads();

    // ---- phase 1: c[i,r] for the 16 own rows. wave wv does rows 4wv..4wv+3
    //      (transient registers only; results to sc) ----
    {
        const int wv = tid >> 6, lane = tid & 63;
        float4 w0 = *(const float4*)(Wc + h * 512 + lane * 4);
        float4 w1 = *(const float4*)(Wc + h * 512 + (64 + lane) * 4);
        #pragma unroll
        for (int q = 0; q < 4; ++q) {
            int lrow = pad + wv * 4 + q;
            float x0 = (float)sx[lrow * 128 + lane];
            float x1 = (float)sx[lrow * 128 + 64 + lane];
            float p0 = x0 * w0.x + x1 * w1.x;
            float p1 = x0 * w0.y + x1 * w1.y;
            float p2 = x0 * w0.z + x1 * w1.z;
            float p3 = x0 * w0.w + x1 * w1.w;
            #pragma unroll
            for (int off = 1; off < 64; off <<= 1) {
                p0 += __shfl_xor(p0, off);
                p1 += __shfl_xor(p1, off);
                p2 += __shfl_xor(p2, off);
                p3 += __shfl_xor(p3, off);
            }
            if (lane == 0) {
                sc[(wv * 4 + q) * 4 + 0] = p0;
                sc[(wv * 4 + q) * 4 + 1] = p1;
                sc[(wv * 4 + q) * 4 + 2] = p2;
                sc[(wv * 4 + q) * 4 + 3] = p3;
            }
        }
    }
    __syncthreads();

    // ---- phase 2: conv + mix (identical to proven R7 structure) ----
    const int d   = tid & 127;
    const int sub = tid >> 7;
    const int lr0 = sub * 8;
    const int nb  = (r0 & 4095) + sub * 8;

    float w[T + K - 1];
    #pragma unroll
    for (int j = 0; j < T + K - 1; ++j) {
        int nl = nb + j - pad;
        float v = (float)sx[(lr0 + j) * 128 + d];
        w[j] = (nl >= 0 && nl < 4096) ? v : 0.f;
    }

    float s0[T] = {}, s1[T] = {}, s2[T] = {}, s3[T] = {}, tv[T] = {};
    const float* Ah = Aw + h * 84;
    #pragma unroll
    for (int j = 0; j < K; ++j) {
        float a0 = Ah[j], a1 = Ah[21 + j], a2 = Ah[42 + j], a3 = Ah[63 + j];
        float bbj = sB[j * 128 + d];
        #pragma unroll
        for (int t = 0; t < T; ++t) {
            float x = w[t + j];
            s0[t] += a0 * x; s1[t] += a1 * x;
            s2[t] += a2 * x; s3[t] += a3 * x;
            tv[t] += bbj * x;
        }
    }

    float v0 = Vw[h * 512 + d],       v1 = Vw[h * 512 + 128 + d];
    float v2 = Vw[h * 512 + 256 + d], v3 = Vw[h * 512 + 384 + d];
    #pragma unroll
    for (int t = 0; t < T; ++t) {
        int rowo = r0 + sub * 8 + t;
        float c0 = sc[(sub * 8 + t) * 4 + 0];
        float c1 = sc[(sub * 8 + t) * 4 + 1];
        float c2 = sc[(sub * 8 + t) * 4 + 2];
        float c3 = sc[(sub * 8 + t) * 4 + 3];
        float o = alpha * (c0 * v0 * s0[t] + c1 * v1 * s1[t] +
                           c2 * v2 * s2[t] + c3 * v3 * s3[t])
                + (1.f - alpha) * tv[t];
        y[(size_t)rowo * 1024 + h * 128 + d] = (bf16)o;
    }
}

__global__ __launch_bounds__(256, 4) void head_mix6(
    const bf16* __restrict__ xpb, const float* __restrict__ Wc,
    const float* __restrict__ Aw, const float* __restrict__ Vw,
    const float* __restrict__ basew, const float* __restrict__ alphas,
    bf16* __restrict__ y)
{
    __shared__ __align__(16) bf16  sx[36 * 128];   // 9216 B (max K=21)
    __shared__ __align__(16) float sB[21 * 128];   // 10752 B
    __shared__ float sc[16 * 4];                   // 256 B
    const int h  = blockIdx.y;
    const int r0 = blockIdx.x * 16;
    const float alpha = 1.f / (1.f + __expf(-alphas[h]));

    switch (KS_c[h]) {
        case 3:  mix_body6<3 >(h, threadIdx.x, r0, xpb, Wc, Aw, Vw, basew, alpha, y, sx, sB, sc); break;
        case 7:  mix_body6<7 >(h, threadIdx.x, r0, xpb, Wc, Aw, Vw, basew, alpha, y, sx, sB, sc); break;
        case 11: mix_body6<11>(h, threadIdx.x, r0, xpb, Wc, Aw, Vw, basew, alpha, y, sx, sB, sc); break;
        default: mix_body6<21>(h, threadIdx.x, r0, xpb, Wc, Aw, Vw, basew, alpha, y, sx, sB, sc); break;
    }
}

// ---------------------------------------------------------------------------
extern "C" void kernel_launch(void* const* d_in, const int* in_sizes, int n_in,
                              void* d_out, int out_size, void* d_ws, size_t ws_size,
                              hipStream_t stream)
{
    const float* x      = (const float*)d_in[0];
    const float* W_in   = (const float*)d_in[1];
    const float* b_in   = (const float*)d_in[2];
    const float* W_out  = (const float*)d_in[3];
    const float* b_out  = (const float*)d_in[4];
    const float* Wc     = (const float*)d_in[5];
    const float* Aw     = (const float*)d_in[6];
    const float* Vw     = (const float*)d_in[7];
    const float* basew  = (const float*)d_in[8];
    const float* alphas = (const float*)d_in[9];
    float* out = (float*)d_out;

    const size_t MB = 1u << 20;
    char* ws = (char*)d_ws;
    bf16*  xb   = (bf16*) (ws);             // 16 MB: x bf16
    bf16*  wib  = (bf16*) (ws + 16 * MB);   //  2 MB: W_in bf16
    bf16*  wob  = (bf16*) (ws + 18 * MB);   //  2 MB: W_out bf16
    bf16*  xpb  = (bf16*) (ws + 20 * MB);   // 16 MB: x_proj bf16
    bf16*  yb   = (bf16*) (ws + 36 * MB);   // 16 MB: head-concat y bf16

    const int NTOT8 = (2 * 4096 * 1024 + 2 * 1024 * 1024) / 8;

    cast_all_kernel<<<NTOT8 / 256, 256, 0, stream>>>(x, xb, W_in, wib, W_out, wob);

    gemm_nt<bf16><<<dim3(8192 / BM, 1024 / BN), 256, 0, stream>>>(
        xb, wib, b_in, xpb, 8192, 1024, 1024);

    head_mix6<<<dim3(512, 8), 256, 0, stream>>>(
        xpb, Wc, Aw, Vw, basew, alphas, yb);

    gemm_nt<float><<<dim3(8192 / BM, 1024 / BN), 256, 0, stream>>>(
        yb, wob, b_out, out, 8192, 1024, 1024);
}